// Round 13
// baseline (23085.597 us; speedup 1.0000x reference)
//
#include <hip/hip_runtime.h>

// Problem constants
#define T_SEQ   8192
#define N_RES   2048
#define K_IN    512

// Geometry: 64 blocks x 512 threads (8 waves); 32 rows/block, 4 rows/wave.
// No LDS, no barriers: every wave is autonomous.
#define G_BLOCKS 64
#define B_THREADS 512
#define ROWS_PER_WAVE 4
#define ROWS_PER_BLOCK 32
static_assert(G_BLOCKS * ROWS_PER_BLOCK == N_RES, "row partition mismatch");

#define INV_SQRT_N 0.022097086912079612f

// Phase encoding: packet float e = phi*(v + ENC_OFF), phi alternates per ring
// generation (phi(g) = ((g>>1)&1) ? -1 : +1, slot = g&1). |v| <= 0.0222 so
// |e| in [0.078, 0.122]. Ready iff phi_expected*e > ENC_THR; stale (gen-2)
// packet has opposite phi -> not-ready; zero-init -> not-ready. Every 32-bit
// word is independently self-validating -> non-atomic 16B accesses are legal.
#define ENC_OFF 0.1f
#define ENC_THR 0.05f

typedef unsigned long long u64;
typedef unsigned int u32;
typedef float f32x2 __attribute__((ext_vector_type(2)));
typedef float f32x4 __attribute__((ext_vector_type(4)));

__device__ __forceinline__ float fast_tanh(float v) {
    float e = __expf(2.0f * v);
    return 1.0f - 2.0f / (e + 1.0f);
}

// Coherent 16B ops at the agent coherence point (sc0 sc1 = bypass L1+L2).
#define ISSUE4(dst, ptr, OFFSTR) \
    asm volatile("global_load_dwordx4 %0, %1, off offset:" OFFSTR " sc0 sc1" \
                 : "=v"(dst) : "v"(ptr))

__device__ __forceinline__ void store_f4_coh(float* p, f32x4 v) {
    asm volatile("global_store_dwordx4 %0, %1, off sc0 sc1"
                 :: "v"(p), "v"(v) : "memory");
}

// DPP full-wave sum; ctrl must be a compile-time constant -> template param.
template<int CTRL>
__device__ __forceinline__ float dpp_add(float a) {
    int s = __builtin_amdgcn_update_dpp(0, __float_as_int(a), CTRL, 0xf, 0xf, false);
    return a + __int_as_float(s);
}
__device__ __forceinline__ float wave_sum(float a) {
    a = dpp_add<0x111>(a);  // row_shr:1
    a = dpp_add<0x112>(a);  // row_shr:2
    a = dpp_add<0x114>(a);  // row_shr:4
    a = dpp_add<0x118>(a);  // row_shr:8
    a = dpp_add<0x142>(a);  // row_bcast:15
    a = dpp_add<0x143>(a);  // row_bcast:31
    return __int_as_float(__builtin_amdgcn_readlane(__float_as_int(a), 63));
}

#define KEEP2(v) asm("" : "+v"(v))

// d_ws layout: ring [2][2048] f32 (16 KB)
__global__ __launch_bounds__(B_THREADS, 2)
void reservoir_v12(const float* __restrict__ input,   // [T_SEQ][K_IN]
                   const float* __restrict__ state0,  // [N_RES]
                   const float* __restrict__ W_in,    // [N_RES][K_IN]
                   const float* __restrict__ W_res,   // [N_RES][N_RES]
                   float* __restrict__ out,           // [T_SEQ+1][N_RES]
                   float* __restrict__ ring)
{
    const int tid  = threadIdx.x;
    const int lane = tid & 63;
    const int wave = tid >> 6;
    const int blk  = blockIdx.x;
    const int r0   = blk * ROWS_PER_BLOCK + wave * ROWS_PER_WAVE;

    // ---- weights as packed f32x2: lane l owns cols {4l+256i} (i=0..7) ----
    f32x2 wr2[ROWS_PER_WAVE][16];   // W_res row k, pairs (4l+256i)+{0,1},{2,3}
    f32x2 wi2[ROWS_PER_WAVE][4];
    #pragma unroll
    for (int k = 0; k < ROWS_PER_WAVE; ++k) {
        const float* rrow = W_res + (size_t)(r0 + k) * N_RES;
        #pragma unroll
        for (int i = 0; i < 8; ++i) {
            float4 w = *reinterpret_cast<const float4*>(rrow + 4 * lane + 256 * i);
            wr2[k][2 * i]     = (f32x2){w.x, w.y};
            wr2[k][2 * i + 1] = (f32x2){w.z, w.w};
        }
        const float* irow = W_in + (size_t)(r0 + k) * K_IN;
        #pragma unroll
        for (int i = 0; i < 2; ++i) {
            float4 w = *reinterpret_cast<const float4*>(irow + 4 * lane + 256 * i);
            wi2[k][2 * i]     = (f32x2){w.x, w.y};
            wi2[k][2 * i + 1] = (f32x2){w.z, w.w};
        }
    }

    // out row 0 = initial state
    if (blk == 0)
        for (int j = tid; j < N_RES; j += B_THREADS) out[j] = state0[j];

    // x row 0 as packed pairs (layout matches wi cols {4l+256i})
    f32x2 xv[4];
    {
        float4 a = *reinterpret_cast<const float4*>(input + 4 * lane);
        float4 b = *reinterpret_cast<const float4*>(input + 4 * lane + 256);
        xv[0] = (f32x2){a.x, a.y}; xv[1] = (f32x2){a.z, a.w};
        xv[2] = (f32x2){b.x, b.y}; xv[3] = (f32x2){b.z, b.w};
    }

    for (int t = 0; t < T_SEQ; ++t) {
        // issue x_{t+1} prefetch early: HBM latency hides under the poll
        f32x2 xn[4] = {xv[0], xv[1], xv[2], xv[3]};
        if (t + 1 < T_SEQ) {
            const float* xr = input + (size_t)(t + 1) * K_IN;
            float4 a = *reinterpret_cast<const float4*>(xr + 4 * lane);
            float4 b = *reinterpret_cast<const float4*>(xr + 4 * lane + 256);
            xn[0] = (f32x2){a.x, a.y}; xn[1] = (f32x2){a.z, a.w};
            xn[2] = (f32x2){b.x, b.y}; xn[3] = (f32x2){b.z, b.w};
        }

        // ---- input contribution (fills wait time) ----
        f32x2 acc2[ROWS_PER_WAVE];
        #pragma unroll
        for (int k = 0; k < ROWS_PER_WAVE; ++k) {
            f32x2 a = (f32x2){0.0f, 0.0f};
            #pragma unroll
            for (int i = 0; i < 4; ++i)
                a = __builtin_elementwise_fma(wi2[k][i], xv[i], a);
            acc2[k] = a;
        }

        // ---- state contribution ----
        if (t == 0) {
            #pragma unroll
            for (int i = 0; i < 8; ++i) {
                float4 s = *reinterpret_cast<const float4*>(state0 + 4 * lane + 256 * i);
                f32x2 s01 = (f32x2){s.x, s.y}, s23 = (f32x2){s.z, s.w};
                #pragma unroll
                for (int k = 0; k < ROWS_PER_WAVE; ++k) {
                    acc2[k] = __builtin_elementwise_fma(wr2[k][2 * i],     s01, acc2[k]);
                    acc2[k] = __builtin_elementwise_fma(wr2[k][2 * i + 1], s23, acc2[k]);
                }
            }
        } else {
            // ---- wave-autonomous fused poll: lane l polls its 8 packets at
            // cols {4l+256i}; each load instr = 1KB contiguous per wave.
            // Pending mask is WAVE-UNIFORM (__all) -> no divergent retries.
            const float phi = ((t >> 1) & 1) ? -1.0f : 1.0f;
            const f32x2 phi2  = {phi, phi};
            const f32x2 noff2 = {-ENC_OFF, -ENC_OFF};
            const float* rpA = ring + ((t & 1) << 11) + 4 * lane;   // i=0..3
            const float* rpB = rpA + 1024;                          // i=4..7
            f32x4 e0, e1, e2, e3, e4, e5, e6, e7;
            u32 pend = 0xFFu;

            ISSUE4(e0, rpA, "0");    ISSUE4(e1, rpA, "1024");
            ISSUE4(e2, rpA, "2048"); ISSUE4(e3, rpA, "3072");
            ISSUE4(e4, rpB, "0");    ISSUE4(e5, rpB, "1024");
            ISSUE4(e6, rpB, "2048"); ISSUE4(e7, rpB, "3072");

            for (;;) {
                asm volatile("s_waitcnt vmcnt(0)"
                             : "+v"(e0), "+v"(e1), "+v"(e2), "+v"(e3),
                               "+v"(e4), "+v"(e5), "+v"(e6), "+v"(e7) :: "memory");
                __builtin_amdgcn_sched_barrier(0);

                #define PROC(IBIT, eN, WIDX)                                        \
                    if (pend & (1u << IBIT)) {                                      \
                        float m0 = fminf(phi * eN.x, phi * eN.y);                   \
                        float m1 = fminf(phi * eN.z, phi * eN.w);                   \
                        if (__all(fminf(m0, m1) > ENC_THR)) {                       \
                            f32x2 s01 = __builtin_elementwise_fma(                  \
                                phi2, (f32x2){eN.x, eN.y}, noff2);                  \
                            f32x2 s23 = __builtin_elementwise_fma(                  \
                                phi2, (f32x2){eN.z, eN.w}, noff2);                  \
                            _Pragma("unroll")                                       \
                            for (int k = 0; k < ROWS_PER_WAVE; ++k) {               \
                                acc2[k] = __builtin_elementwise_fma(                \
                                    wr2[k][2 * WIDX], s01, acc2[k]);                \
                                acc2[k] = __builtin_elementwise_fma(                \
                                    wr2[k][2 * WIDX + 1], s23, acc2[k]);            \
                            }                                                       \
                            pend &= ~(1u << IBIT);                                  \
                        }                                                           \
                    }
                PROC(0, e0, 0) PROC(1, e1, 1) PROC(2, e2, 2) PROC(3, e3, 3)
                PROC(4, e4, 4) PROC(5, e5, 5) PROC(6, e6, 6) PROC(7, e7, 7)
                #undef PROC

                if (!pend) break;
                __builtin_amdgcn_s_sleep(1);
                if (pend & 0x01u) ISSUE4(e0, rpA, "0");
                if (pend & 0x02u) ISSUE4(e1, rpA, "1024");
                if (pend & 0x04u) ISSUE4(e2, rpA, "2048");
                if (pend & 0x08u) ISSUE4(e3, rpA, "3072");
                if (pend & 0x10u) ISSUE4(e4, rpB, "0");
                if (pend & 0x20u) ISSUE4(e5, rpB, "1024");
                if (pend & 0x40u) ISSUE4(e6, rpB, "2048");
                if (pend & 0x80u) ISSUE4(e7, rpB, "3072");
            }
        }

        // ---- DPP full-wave reduce (4 rows interleaved), results uniform ----
        const float t0 = wave_sum(acc2[0].x + acc2[0].y);
        const float t1 = wave_sum(acc2[1].x + acc2[1].y);
        const float t2 = wave_sum(acc2[2].x + acc2[2].y);
        const float t3 = wave_sum(acc2[3].x + acc2[3].y);

        const float v0 = fast_tanh(t0) * INV_SQRT_N;
        const float v1 = fast_tanh(t1) * INV_SQRT_N;
        const float v2 = fast_tanh(t2) * INV_SQRT_N;
        const float v3 = fast_tanh(t3) * INV_SQRT_N;

        const int   slotn = (t + 1) & 1;
        const float phin  = (((t + 1) >> 1) & 1) ? -1.0f : 1.0f;
        if (lane == 0) {
            f32x4 pk = {phin * (v0 + ENC_OFF), phin * (v1 + ENC_OFF),
                        phin * (v2 + ENC_OFF), phin * (v3 + ENC_OFF)};
            store_f4_coh(ring + (slotn << 11) + r0, pk);
        } else if (lane == 2) {
            // per-wave out store (rows r0..r0+3) — off the critical path
            *reinterpret_cast<float4*>(out + (size_t)(t + 1) * N_RES + r0) =
                make_float4(v0, v1, v2, v3);
        }

        // ---- pin weights across the back edge ----
        #pragma unroll
        for (int k = 0; k < ROWS_PER_WAVE; ++k) {
            #pragma unroll
            for (int i = 0; i < 16; ++i) KEEP2(wr2[k][i]);
            #pragma unroll
            for (int i = 0; i < 4; ++i)  KEEP2(wi2[k][i]);
        }

        #pragma unroll
        for (int i = 0; i < 4; ++i) xv[i] = xn[i];
    }
}

extern "C" void kernel_launch(void* const* d_in, const int* in_sizes, int n_in,
                              void* d_out, int out_size, void* d_ws, size_t ws_size,
                              hipStream_t stream) {
    const float* input  = (const float*)d_in[0];
    const float* state0 = (const float*)d_in[1];
    const float* W_in   = (const float*)d_in[2];
    const float* W_res  = (const float*)d_in[3];
    float* out  = (float*)d_out;
    float* ring = (float*)d_ws;

    // zero = "not ready" for both phases; re-cleared on every call/replay
    hipMemsetAsync(d_ws, 0, 2 * N_RES * sizeof(float), stream);

    void* args[] = { (void*)&input, (void*)&state0, (void*)&W_in, (void*)&W_res,
                     (void*)&out, (void*)&ring };
    hipLaunchCooperativeKernel((const void*)reservoir_v12,
                               dim3(G_BLOCKS), dim3(B_THREADS),
                               args, 0, stream);
}